// Round 1
// baseline (1138.916 us; speedup 1.0000x reference)
//
#include <hip/hip_runtime.h>

#define N_NODES 50000
#define N_EDGES 800000
#define DIN     128
#define H       96
#define K_EXP   8
#define L_LAYERS 4
#define C_OUT   40

// ---------------- CSR build ----------------

__global__ void count_deg(const int* __restrict__ row, int* __restrict__ deg, int e) {
    int i = blockIdx.x * blockDim.x + threadIdx.x;
    if (i < e) atomicAdd(&deg[row[i]], 1);
}

__global__ void scan_rowptr(const int* __restrict__ deg, int* __restrict__ rowptr, int n) {
    __shared__ int wsum[16];
    __shared__ int carry_s;
    int tid  = threadIdx.x;
    int lane = tid & 63, wid = tid >> 6;
    if (tid == 0) { carry_s = 0; rowptr[0] = 0; }
    __syncthreads();
    for (int base = 0; base < n; base += 1024) {
        int idx = base + tid;
        int v = (idx < n) ? deg[idx] : 0;
        int s = v;
        #pragma unroll
        for (int off = 1; off < 64; off <<= 1) {
            int t = __shfl_up(s, off, 64);
            if (lane >= off) s += t;
        }
        if (lane == 63) wsum[wid] = s;
        __syncthreads();
        if (wid == 0 && lane < 16) {
            int w = wsum[lane];
            #pragma unroll
            for (int off = 1; off < 16; off <<= 1) {
                int t = __shfl_up(w, off, 16);
                if (lane >= off) w += t;
            }
            wsum[lane] = w;
        }
        __syncthreads();
        int waveoff = (wid == 0) ? 0 : wsum[wid - 1];
        int carry = carry_s;
        if (idx < n) rowptr[idx + 1] = carry + waveoff + s;
        __syncthreads();
        if (tid == 1023) carry_s = carry + wsum[15];
        __syncthreads();
    }
}

__global__ void scatter_edges(const int* __restrict__ row, const int* __restrict__ col,
                              const int* __restrict__ rowptr, int* __restrict__ cur,
                              int* __restrict__ csr, int e) {
    int i = blockIdx.x * blockDim.x + threadIdx.x;
    if (i < e) {
        int r = row[i];
        int p = atomicAdd(&cur[r], 1);
        csr[rowptr[r] + p] = col[i];
    }
}

// ---------------- SpMM: hi[r] = sum over edges (r,c) of h[c] ----------------
// 32 lanes per row, 3 features per lane (96 = 32*3). 8 rows per 256-thread block.

__global__ __launch_bounds__(256) void spmm_kernel(const float* __restrict__ h,
                                                   const int* __restrict__ rowptr,
                                                   const int* __restrict__ csr,
                                                   float* __restrict__ hi, int n) {
    int r  = blockIdx.x * 8 + (threadIdx.x >> 5);
    int li = threadIdx.x & 31;
    if (r >= n) return;
    int start = rowptr[r], end = rowptr[r + 1];
    float a0 = 0.f, a1 = 0.f, a2 = 0.f;
    for (int j0 = start; j0 < end; j0 += 32) {
        int m = end - j0; if (m > 32) m = 32;
        int c = 0;
        if (li < m) c = csr[j0 + li];
        for (int t = 0; t < m; t++) {
            int cc = __shfl(c, t, 32);
            const float* hp = h + (size_t)cc * H;
            a0 += hp[li];
            a1 += hp[li + 32];
            a2 += hp[li + 64];
        }
    }
    float* op = hi + (size_t)r * H;
    op[li] = a0; op[li + 32] = a1; op[li + 64] = a2;
}

// ---------------- ctx + softmax: z = softmax(h @ ctx_w + ctx_b) ----------------
// 8 lanes per node, lane = expert.

__global__ __launch_bounds__(256) void ctx_softmax(const float* __restrict__ h,
                                                   const float* __restrict__ cw,
                                                   const float* __restrict__ cb,
                                                   float* __restrict__ z, int n) {
    int idx  = blockIdx.x * blockDim.x + threadIdx.x;
    int node = idx >> 3, k = idx & 7;
    if (node >= n) return;
    const float* hr = h + (size_t)node * H;
    float acc = cb[k];
    #pragma unroll 8
    for (int d = 0; d < H; d++) acc += hr[d] * cw[d * K_EXP + k];
    float mx = acc;
    #pragma unroll
    for (int off = 4; off >= 1; off >>= 1) mx = fmaxf(mx, __shfl_xor(mx, off, 8));
    float e = __expf(acc - mx);
    float s = e;
    #pragma unroll
    for (int off = 4; off >= 1; off >>= 1) s += __shfl_xor(s, off, 8);
    z[(size_t)node * K_EXP + k] = e / s;
}

// ---------------- fc0: h = relu(x @ W + b), x[N,128], W[128,96] ----------------
// 64-row tile, 256 threads, thread = 4 rows x 6 cols, K chunked by 64.

__global__ __launch_bounds__(256) void fc0_kernel(const float* __restrict__ x,
                                                  const float* __restrict__ w,
                                                  const float* __restrict__ b,
                                                  float* __restrict__ h, int n) {
    __shared__ float xs[64][65];
    __shared__ float ws[64][96];
    int tid = threadIdx.x;
    int ty = tid >> 4, tx = tid & 15;
    int row0 = blockIdx.x * 64;
    float acc[4][6] = {};
    for (int dc = 0; dc < DIN; dc += 64) {
        __syncthreads();
        for (int t = tid; t < 64 * 64; t += 256) {
            int m = t >> 6, d = t & 63;
            int gr = row0 + m;
            xs[m][d] = (gr < n) ? x[(size_t)gr * DIN + dc + d] : 0.f;
        }
        for (int t = tid; t < 64 * 96; t += 256) {
            int d = t / 96, o = t - d * 96;
            ws[d][o] = w[(size_t)(dc + d) * H + o];
        }
        __syncthreads();
        #pragma unroll 4
        for (int d = 0; d < 64; d++) {
            float a[4], bb[6];
            #pragma unroll
            for (int j = 0; j < 4; j++) a[j] = xs[ty * 4 + j][d];
            #pragma unroll
            for (int j = 0; j < 6; j++) bb[j] = ws[d][tx * 6 + j];
            #pragma unroll
            for (int j = 0; j < 4; j++)
                #pragma unroll
                for (int jj = 0; jj < 6; jj++) acc[j][jj] += a[j] * bb[jj];
        }
    }
    #pragma unroll
    for (int j = 0; j < 4; j++) {
        int gr = row0 + ty * 4 + j;
        if (gr < n) {
            #pragma unroll
            for (int jj = 0; jj < 6; jj++) {
                int o = tx * 6 + jj;
                h[(size_t)gr * H + o] = fmaxf(acc[j][jj] + b[o], 0.f);
            }
        }
    }
}

// ---------------- expert GEMM + weighted combine + residual + relu ----------------
// out[m,o] = relu( sum_k z[m,k] * (hi[m,:] @ Wk[:,o]) + hin[m,o] )
// 64-row tile, 256 threads, thread = 4 rows x 6 cols, loop over 8 experts.

__global__ __launch_bounds__(256) void expert_gemm(const float* __restrict__ hi,
                                                   const float* __restrict__ hin,
                                                   const float* __restrict__ conv_w,
                                                   const float* __restrict__ z,
                                                   float* __restrict__ hout, int n) {
    __shared__ float as[64][97];   // hi tile [m][d]
    __shared__ float ws[96][96];   // W_k [d][o]
    __shared__ float zs[64][9];
    int tid = threadIdx.x;
    int ty = tid >> 4, tx = tid & 15;
    int row0 = blockIdx.x * 64;
    for (int t = tid; t < 64 * 96; t += 256) {
        int m = t / 96, d = t - m * 96;
        int gr = row0 + m;
        as[m][d] = (gr < n) ? hi[(size_t)gr * H + d] : 0.f;
    }
    for (int t = tid; t < 64 * 8; t += 256) {
        int m = t >> 3, k = t & 7;
        int gr = row0 + m;
        zs[m][k] = (gr < n) ? z[(size_t)gr * K_EXP + k] : 0.f;
    }
    float acc[4][6] = {};
    for (int k = 0; k < K_EXP; k++) {
        __syncthreads();
        const float* wk = conv_w + (size_t)k * H * H;
        for (int t = tid; t < 96 * 96; t += 256) {
            int d = t / 96, o = t - d * 96;
            ws[d][o] = wk[t];
        }
        __syncthreads();
        float tmp[4][6] = {};
        #pragma unroll 2
        for (int d = 0; d < 96; d++) {
            float a[4], bb[6];
            #pragma unroll
            for (int j = 0; j < 4; j++) a[j] = as[ty * 4 + j][d];
            #pragma unroll
            for (int j = 0; j < 6; j++) bb[j] = ws[d][tx * 6 + j];
            #pragma unroll
            for (int j = 0; j < 4; j++)
                #pragma unroll
                for (int jj = 0; jj < 6; jj++) tmp[j][jj] += a[j] * bb[jj];
        }
        #pragma unroll
        for (int j = 0; j < 4; j++) {
            float zv = zs[ty * 4 + j][k];
            #pragma unroll
            for (int jj = 0; jj < 6; jj++) acc[j][jj] += zv * tmp[j][jj];
        }
    }
    #pragma unroll
    for (int j = 0; j < 4; j++) {
        int gr = row0 + ty * 4 + j;
        if (gr < n) {
            #pragma unroll
            for (int jj = 0; jj < 6; jj++) {
                int o = tx * 6 + jj;
                float v = acc[j][jj] + hin[(size_t)gr * H + o];
                hout[(size_t)gr * H + o] = fmaxf(v, 0.f);
            }
        }
    }
}

// ---------------- fc1: out = h @ W + b, W[96,40] ----------------
// 64-row tile, 256 threads = 32 row-groups (TM=2) x 8 col-groups (TO=5).

__global__ __launch_bounds__(256) void fc1_kernel(const float* __restrict__ h,
                                                  const float* __restrict__ w,
                                                  const float* __restrict__ b,
                                                  float* __restrict__ out, int n) {
    __shared__ float hs[64][97];
    __shared__ float ws[96][40];
    int tid = threadIdx.x;
    int ty = tid >> 3;   // 0..31
    int tx = tid & 7;    // 0..7
    int row0 = blockIdx.x * 64;
    for (int t = tid; t < 64 * 96; t += 256) {
        int m = t / 96, d = t - m * 96;
        int gr = row0 + m;
        hs[m][d] = (gr < n) ? h[(size_t)gr * H + d] : 0.f;
    }
    for (int t = tid; t < 96 * 40; t += 256) {
        int d = t / 40, o = t - d * 40;
        ws[d][o] = w[t];
    }
    __syncthreads();
    float acc[2][5] = {};
    #pragma unroll 4
    for (int d = 0; d < 96; d++) {
        float a[2], bb[5];
        a[0] = hs[ty * 2][d];
        a[1] = hs[ty * 2 + 1][d];
        #pragma unroll
        for (int j = 0; j < 5; j++) bb[j] = ws[d][tx * 5 + j];
        #pragma unroll
        for (int j = 0; j < 2; j++)
            #pragma unroll
            for (int jj = 0; jj < 5; jj++) acc[j][jj] += a[j] * bb[jj];
    }
    #pragma unroll
    for (int j = 0; j < 2; j++) {
        int gr = row0 + ty * 2 + j;
        if (gr < n) {
            #pragma unroll
            for (int jj = 0; jj < 5; jj++) {
                int o = tx * 5 + jj;
                out[(size_t)gr * C_OUT + o] = acc[j][jj] + b[o];
            }
        }
    }
}

// ---------------- launch ----------------

extern "C" void kernel_launch(void* const* d_in, const int* in_sizes, int n_in,
                              void* d_out, int out_size, void* d_ws, size_t ws_size,
                              hipStream_t stream) {
    const float* x      = (const float*)d_in[0];
    const int*   ei     = (const int*)d_in[1];
    const float* fc0_w  = (const float*)d_in[2];
    const float* fc0_b  = (const float*)d_in[3];
    const float* fc1_w  = (const float*)d_in[4];
    const float* fc1_b  = (const float*)d_in[5];
    const float* ctx_w  = (const float*)d_in[6];
    const float* ctx_b  = (const float*)d_in[7];
    const float* conv_w = (const float*)d_in[8];
    float* out = (float*)d_out;

    float* h0   = (float*)d_ws;
    float* h1   = h0 + (size_t)N_NODES * H;
    float* hi   = h1 + (size_t)N_NODES * H;
    float* zbuf = hi + (size_t)N_NODES * H;
    int* rowptr = (int*)(zbuf + (size_t)N_NODES * K_EXP);
    int* deg    = rowptr + (N_NODES + 1);
    int* cur    = deg + N_NODES;
    int* csr    = cur + N_NODES;

    const int* row = ei;
    const int* col = ei + N_EDGES;

    // deg and cur are contiguous: one memset clears both
    hipMemsetAsync(deg, 0, sizeof(int) * 2 * N_NODES, stream);

    count_deg<<<(N_EDGES + 255) / 256, 256, 0, stream>>>(row, deg, N_EDGES);
    scan_rowptr<<<1, 1024, 0, stream>>>(deg, rowptr, N_NODES);
    scatter_edges<<<(N_EDGES + 255) / 256, 256, 0, stream>>>(row, col, rowptr, cur, csr, N_EDGES);

    int gemm_grid = (N_NODES + 63) / 64;
    fc0_kernel<<<gemm_grid, 256, 0, stream>>>(x, fc0_w, fc0_b, h0, N_NODES);

    float* hcur = h0;
    float* hnext = h1;
    for (int i = 0; i < L_LAYERS; i++) {
        ctx_softmax<<<(N_NODES * K_EXP + 255) / 256, 256, 0, stream>>>(
            hcur, ctx_w + (size_t)i * H * K_EXP, ctx_b + (size_t)i * K_EXP, zbuf, N_NODES);
        spmm_kernel<<<(N_NODES + 7) / 8, 256, 0, stream>>>(hcur, rowptr, csr, hi, N_NODES);
        expert_gemm<<<gemm_grid, 256, 0, stream>>>(
            hi, hcur, conv_w + (size_t)i * K_EXP * H * H, zbuf, hnext, N_NODES);
        float* t = hcur; hcur = hnext; hnext = t;
    }
    fc1_kernel<<<gemm_grid, 256, 0, stream>>>(hcur, fc1_w, fc1_b, out, N_NODES);
}

// Round 2
// 651.158 us; speedup vs baseline: 1.7491x; 1.7491x over previous
//
#include <hip/hip_runtime.h>

#define N_NODES 50000
#define N_EDGES 800000
#define DIN     128
#define H       96
#define K_EXP   8
#define L_LAYERS 4
#define C_OUT   40

typedef _Float16 f16;
typedef f16 f16x8 __attribute__((ext_vector_type(8)));
typedef float f32x4 __attribute__((ext_vector_type(4)));

// ---------------- CSR build ----------------

__global__ void count_deg(const int* __restrict__ row, int* __restrict__ deg, int e) {
    int i = blockIdx.x * blockDim.x + threadIdx.x;
    if (i < e) atomicAdd(&deg[row[i]], 1);
}

__global__ void scan_rowptr(const int* __restrict__ deg, int* __restrict__ rowptr, int n) {
    __shared__ int wsum[16];
    __shared__ int carry_s;
    int tid  = threadIdx.x;
    int lane = tid & 63, wid = tid >> 6;
    if (tid == 0) { carry_s = 0; rowptr[0] = 0; }
    __syncthreads();
    for (int base = 0; base < n; base += 1024) {
        int idx = base + tid;
        int v = (idx < n) ? deg[idx] : 0;
        int s = v;
        #pragma unroll
        for (int off = 1; off < 64; off <<= 1) {
            int t = __shfl_up(s, off, 64);
            if (lane >= off) s += t;
        }
        if (lane == 63) wsum[wid] = s;
        __syncthreads();
        if (wid == 0 && lane < 16) {
            int w = wsum[lane];
            #pragma unroll
            for (int off = 1; off < 16; off <<= 1) {
                int t = __shfl_up(w, off, 16);
                if (lane >= off) w += t;
            }
            wsum[lane] = w;
        }
        __syncthreads();
        int waveoff = (wid == 0) ? 0 : wsum[wid - 1];
        int carry = carry_s;
        if (idx < n) rowptr[idx + 1] = carry + waveoff + s;
        __syncthreads();
        if (tid == 1023) carry_s = carry + wsum[15];
        __syncthreads();
    }
}

__global__ void scatter_edges(const int* __restrict__ row, const int* __restrict__ col,
                              const int* __restrict__ rowptr, int* __restrict__ cur,
                              int* __restrict__ csr, int e) {
    int i = blockIdx.x * blockDim.x + threadIdx.x;
    if (i < e) {
        int r = row[i];
        int p = atomicAdd(&cur[r], 1);
        csr[rowptr[r] + p] = col[i];
    }
}

// ---------------- convert conv_w fp32 [K,H,H] (d-major) -> f16 [K,o,d] transposed ----------------

__global__ void convert_w(const float* __restrict__ src, f16* __restrict__ dst, int total) {
    int i = blockIdx.x * blockDim.x + threadIdx.x;
    if (i < total) {
        int o = i % H;
        int t = i / H;
        int d = t % H;
        int lk = t / H;
        dst[(size_t)lk * H * H + o * H + d] = (f16)src[i];
    }
}

// ---------------- SpMM: hi[r] = sum over edges (r,c) of h[c]; writes fp16 ----------------

__global__ __launch_bounds__(256) void spmm_kernel(const float* __restrict__ h,
                                                   const int* __restrict__ rowptr,
                                                   const int* __restrict__ csr,
                                                   f16* __restrict__ hi, int n) {
    int r  = blockIdx.x * 8 + (threadIdx.x >> 5);
    int li = threadIdx.x & 31;
    if (r >= n) return;
    int start = rowptr[r], end = rowptr[r + 1];
    float a0 = 0.f, a1 = 0.f, a2 = 0.f;
    for (int j0 = start; j0 < end; j0 += 32) {
        int m = end - j0; if (m > 32) m = 32;
        int c = 0;
        if (li < m) c = csr[j0 + li];
        for (int t = 0; t < m; t++) {
            int cc = __shfl(c, t, 32);
            const float* hp = h + (size_t)cc * H;
            a0 += hp[li];
            a1 += hp[li + 32];
            a2 += hp[li + 64];
        }
    }
    f16* op = hi + (size_t)r * H;
    op[li] = (f16)a0; op[li + 32] = (f16)a1; op[li + 64] = (f16)a2;
}

// ---------------- ctx + softmax ----------------

__global__ __launch_bounds__(256) void ctx_softmax(const float* __restrict__ h,
                                                   const float* __restrict__ cw,
                                                   const float* __restrict__ cb,
                                                   float* __restrict__ z, int n) {
    int idx  = blockIdx.x * blockDim.x + threadIdx.x;
    int node = idx >> 3, k = idx & 7;
    if (node >= n) return;
    const float* hr = h + (size_t)node * H;
    float acc = cb[k];
    #pragma unroll 8
    for (int d = 0; d < H; d++) acc += hr[d] * cw[d * K_EXP + k];
    float mx = acc;
    #pragma unroll
    for (int off = 4; off >= 1; off >>= 1) mx = fmaxf(mx, __shfl_xor(mx, off, 8));
    float e = __expf(acc - mx);
    float s = e;
    #pragma unroll
    for (int off = 4; off >= 1; off >>= 1) s += __shfl_xor(s, off, 8);
    z[(size_t)node * K_EXP + k] = e / s;
}

// ---------------- fc0 (fp32 vector, minor cost) ----------------

__global__ __launch_bounds__(256) void fc0_kernel(const float* __restrict__ x,
                                                  const float* __restrict__ w,
                                                  const float* __restrict__ b,
                                                  float* __restrict__ h, int n) {
    __shared__ float xs[64][65];
    __shared__ float ws[64][96];
    int tid = threadIdx.x;
    int ty = tid >> 4, tx = tid & 15;
    int row0 = blockIdx.x * 64;
    float acc[4][6] = {};
    for (int dc = 0; dc < DIN; dc += 64) {
        __syncthreads();
        for (int t = tid; t < 64 * 64; t += 256) {
            int m = t >> 6, d = t & 63;
            int gr = row0 + m;
            xs[m][d] = (gr < n) ? x[(size_t)gr * DIN + dc + d] : 0.f;
        }
        for (int t = tid; t < 64 * 96; t += 256) {
            int d = t / 96, o = t - d * 96;
            ws[d][o] = w[(size_t)(dc + d) * H + o];
        }
        __syncthreads();
        #pragma unroll 4
        for (int d = 0; d < 64; d++) {
            float a[4], bb[6];
            #pragma unroll
            for (int j = 0; j < 4; j++) a[j] = xs[ty * 4 + j][d];
            #pragma unroll
            for (int j = 0; j < 6; j++) bb[j] = ws[d][tx * 6 + j];
            #pragma unroll
            for (int j = 0; j < 4; j++)
                #pragma unroll
                for (int jj = 0; jj < 6; jj++) acc[j][jj] += a[j] * bb[jj];
        }
    }
    #pragma unroll
    for (int j = 0; j < 4; j++) {
        int gr = row0 + ty * 4 + j;
        if (gr < n) {
            #pragma unroll
            for (int jj = 0; jj < 6; jj++) {
                int o = tx * 6 + jj;
                h[(size_t)gr * H + o] = fmaxf(acc[j][jj] + b[o], 0.f);
            }
        }
    }
}

// ---------------- expert GEMM via fp16 MFMA ----------------
// out[m,o] = relu( sum_k z[m,k] * (hi[m,:] @ Wk[:,o]) + hin[m,o] )
// Block: 64 rows x 96 cols, 4 waves; wave w = rows 16w..16w+15, 6 col-tiles of 16.
// mfma_f32_16x16x32_f16: A[m=lane&15][k=(lane>>4)*8+j], B[k][n=lane&15],
// C/D: col=lane&15, row=(lane>>4)*4+reg.

#define APAD 104   // 96 + 8 halfs padding: 208B row stride, 16B-aligned, conflict-free

__global__ __launch_bounds__(256) void expert_gemm(const f16* __restrict__ hi16,
                                                   const float* __restrict__ hin,
                                                   const f16* __restrict__ wt,     // [K][o][d] f16
                                                   const float* __restrict__ z,
                                                   float* __restrict__ hout, int n) {
    __shared__ f16 As[64 * APAD];
    __shared__ f16 Ws[96 * APAD];
    __shared__ float Zs[64 * 8];

    int tid = threadIdx.x;
    int l = tid & 63, w = tid >> 6;
    int quad = l >> 4, lc = l & 15;
    int row0 = blockIdx.x * 64;

    // stage A tile (64 x 96 f16) as half8 chunks
    for (int t = tid; t < 768; t += 256) {
        int m = t / 12, c8 = (t % 12) * 8;
        int gr = row0 + m;
        f16x8 v = {};
        if (gr < n) v = *(const f16x8*)(hi16 + (size_t)gr * H + c8);
        *(f16x8*)&As[m * APAD + c8] = v;
    }
    // stage z tile (64 x 8 fp32)
    for (int t = tid; t < 512; t += 256) {
        int m = t >> 3, k = t & 7;
        int gr = row0 + m;
        Zs[m * 8 + k] = (gr < n) ? z[(size_t)gr * K_EXP + k] : 0.f;
    }
    __syncthreads();

    // A fragments: reused across all experts and col-tiles
    f16x8 afr[3];
    #pragma unroll
    for (int ks = 0; ks < 3; ks++)
        afr[ks] = *(const f16x8*)&As[(16 * w + lc) * APAD + ks * 32 + quad * 8];

    f32x4 acc[6] = {};

    for (int k = 0; k < K_EXP; k++) {
        __syncthreads();
        // stage W_k (96 x 96 f16, [o][d])
        const f16* wk = wt + (size_t)k * H * H;
        for (int t = tid; t < 1152; t += 256) {
            int o = t / 12, c8 = (t % 12) * 8;
            *(f16x8*)&Ws[o * APAD + c8] = *(const f16x8*)(wk + o * H + c8);
        }
        __syncthreads();

        float z0 = Zs[(16 * w + quad * 4 + 0) * 8 + k];
        float z1 = Zs[(16 * w + quad * 4 + 1) * 8 + k];
        float z2 = Zs[(16 * w + quad * 4 + 2) * 8 + k];
        float z3 = Zs[(16 * w + quad * 4 + 3) * 8 + k];

        #pragma unroll
        for (int ct = 0; ct < 6; ct++) {
            f32x4 tmp = {};
            #pragma unroll
            for (int ks = 0; ks < 3; ks++) {
                f16x8 bfr = *(const f16x8*)&Ws[(ct * 16 + lc) * APAD + ks * 32 + quad * 8];
                tmp = __builtin_amdgcn_mfma_f32_16x16x32_f16(afr[ks], bfr, tmp, 0, 0, 0);
            }
            acc[ct][0] += z0 * tmp[0];
            acc[ct][1] += z1 * tmp[1];
            acc[ct][2] += z2 * tmp[2];
            acc[ct][3] += z3 * tmp[3];
        }
    }

    // epilogue: residual + relu
    int m0 = 16 * w + quad * 4;
    #pragma unroll
    for (int r = 0; r < 4; r++) {
        int gr = row0 + m0 + r;
        if (gr < n) {
            #pragma unroll
            for (int ct = 0; ct < 6; ct++) {
                int o = ct * 16 + lc;
                float v = acc[ct][r] + hin[(size_t)gr * H + o];
                hout[(size_t)gr * H + o] = fmaxf(v, 0.f);
            }
        }
    }
}

// ---------------- fc1 ----------------

__global__ __launch_bounds__(256) void fc1_kernel(const float* __restrict__ h,
                                                  const float* __restrict__ w,
                                                  const float* __restrict__ b,
                                                  float* __restrict__ out, int n) {
    __shared__ float hs[64][97];
    __shared__ float ws[96][40];
    int tid = threadIdx.x;
    int ty = tid >> 3;   // 0..31
    int tx = tid & 7;    // 0..7
    int row0 = blockIdx.x * 64;
    for (int t = tid; t < 64 * 96; t += 256) {
        int m = t / 96, d = t - m * 96;
        int gr = row0 + m;
        hs[m][d] = (gr < n) ? h[(size_t)gr * H + d] : 0.f;
    }
    for (int t = tid; t < 96 * 40; t += 256) {
        int d = t / 40, o = t - d * 40;
        ws[d][o] = w[t];
    }
    __syncthreads();
    float acc[2][5] = {};
    #pragma unroll 4
    for (int d = 0; d < 96; d++) {
        float a[2], bb[5];
        a[0] = hs[ty * 2][d];
        a[1] = hs[ty * 2 + 1][d];
        #pragma unroll
        for (int j = 0; j < 5; j++) bb[j] = ws[d][tx * 5 + j];
        #pragma unroll
        for (int j = 0; j < 2; j++)
            #pragma unroll
            for (int jj = 0; jj < 5; jj++) acc[j][jj] += a[j] * bb[jj];
    }
    #pragma unroll
    for (int j = 0; j < 2; j++) {
        int gr = row0 + ty * 2 + j;
        if (gr < n) {
            #pragma unroll
            for (int jj = 0; jj < 5; jj++) {
                int o = tx * 5 + jj;
                out[(size_t)gr * C_OUT + o] = acc[j][jj] + b[o];
            }
        }
    }
}

// ---------------- launch ----------------

extern "C" void kernel_launch(void* const* d_in, const int* in_sizes, int n_in,
                              void* d_out, int out_size, void* d_ws, size_t ws_size,
                              hipStream_t stream) {
    const float* x      = (const float*)d_in[0];
    const int*   ei     = (const int*)d_in[1];
    const float* fc0_w  = (const float*)d_in[2];
    const float* fc0_b  = (const float*)d_in[3];
    const float* fc1_w  = (const float*)d_in[4];
    const float* fc1_b  = (const float*)d_in[5];
    const float* ctx_w  = (const float*)d_in[6];
    const float* ctx_b  = (const float*)d_in[7];
    const float* conv_w = (const float*)d_in[8];
    float* out = (float*)d_out;

    float* h0   = (float*)d_ws;
    float* h1   = h0 + (size_t)N_NODES * H;
    float* zbuf = h1 + (size_t)N_NODES * H;
    f16*   hi16 = (f16*)(zbuf + (size_t)N_NODES * K_EXP);
    f16*   wt16 = hi16 + (size_t)N_NODES * H;
    int* rowptr = (int*)(wt16 + (size_t)L_LAYERS * K_EXP * H * H);
    int* deg    = rowptr + (N_NODES + 1);
    int* cur    = deg + N_NODES;
    int* csr    = cur + N_NODES;

    const int* row = ei;
    const int* col = ei + N_EDGES;

    hipMemsetAsync(deg, 0, sizeof(int) * 2 * N_NODES, stream);

    count_deg<<<(N_EDGES + 255) / 256, 256, 0, stream>>>(row, deg, N_EDGES);
    scan_rowptr<<<1, 1024, 0, stream>>>(deg, rowptr, N_NODES);
    scatter_edges<<<(N_EDGES + 255) / 256, 256, 0, stream>>>(row, col, rowptr, cur, csr, N_EDGES);

    int wtotal = L_LAYERS * K_EXP * H * H;
    convert_w<<<(wtotal + 255) / 256, 256, 0, stream>>>(conv_w, wt16, wtotal);

    int gemm_grid = (N_NODES + 63) / 64;
    fc0_kernel<<<gemm_grid, 256, 0, stream>>>(x, fc0_w, fc0_b, h0, N_NODES);

    float* hcur = h0;
    float* hnext = h1;
    for (int i = 0; i < L_LAYERS; i++) {
        ctx_softmax<<<(N_NODES * K_EXP + 255) / 256, 256, 0, stream>>>(
            hcur, ctx_w + (size_t)i * H * K_EXP, ctx_b + (size_t)i * K_EXP, zbuf, N_NODES);
        spmm_kernel<<<(N_NODES + 7) / 8, 256, 0, stream>>>(hcur, rowptr, csr, hi16, N_NODES);
        expert_gemm<<<gemm_grid, 256, 0, stream>>>(
            hi16, hcur, wt16 + (size_t)i * K_EXP * H * H, zbuf, hnext, N_NODES);
        float* t = hcur; hcur = hnext; hnext = t;
    }
    fc1_kernel<<<gemm_grid, 256, 0, stream>>>(hcur, fc1_w, fc1_b, out, N_NODES);
}

// Round 3
// 514.495 us; speedup vs baseline: 2.2137x; 1.2656x over previous
//
#include <hip/hip_runtime.h>

#define N_NODES 50000
#define N_EDGES 800000
#define DIN     128
#define H       96
#define K_EXP   8
#define L_LAYERS 4
#define C_OUT   40

typedef _Float16 f16;
typedef f16 f16x2 __attribute__((ext_vector_type(2)));
typedef f16 f16x4 __attribute__((ext_vector_type(4)));
typedef f16 f16x8 __attribute__((ext_vector_type(8)));
typedef float f32x4 __attribute__((ext_vector_type(4)));

// ---------------- CSR build ----------------

__global__ void count_deg(const int* __restrict__ row, int* __restrict__ deg, int e) {
    int i = blockIdx.x * blockDim.x + threadIdx.x;
    if (i < e) atomicAdd(&deg[row[i]], 1);
}

// per-block inclusive scan of 1024-chunks; partial[bid] = block total
__global__ __launch_bounds__(1024) void scanA(const int* __restrict__ deg,
                                              int* __restrict__ rowptr,
                                              int* __restrict__ partial, int n) {
    __shared__ int wsum[16];
    int tid  = threadIdx.x;
    int lane = tid & 63, wid = tid >> 6;
    int idx = blockIdx.x * 1024 + tid;
    int v = (idx < n) ? deg[idx] : 0;
    int s = v;
    #pragma unroll
    for (int off = 1; off < 64; off <<= 1) {
        int t = __shfl_up(s, off, 64);
        if (lane >= off) s += t;
    }
    if (lane == 63) wsum[wid] = s;
    __syncthreads();
    if (wid == 0 && lane < 16) {
        int w = wsum[lane];
        #pragma unroll
        for (int off = 1; off < 16; off <<= 1) {
            int t = __shfl_up(w, off, 16);
            if (lane >= off) w += t;
        }
        wsum[lane] = w;
    }
    __syncthreads();
    int waveoff = (wid == 0) ? 0 : wsum[wid - 1];
    if (idx < n) rowptr[idx + 1] = waveoff + s;
    if (tid == 1023) partial[blockIdx.x] = waveoff + s;
}

// exclusive scan of block totals (<=64 blocks)
__global__ void scanB(const int* __restrict__ partial, int* __restrict__ blockoff, int nb) {
    int lane = threadIdx.x;
    int v = (lane < nb) ? partial[lane] : 0;
    int s = v;
    #pragma unroll
    for (int off = 1; off < 64; off <<= 1) {
        int t = __shfl_up(s, off, 64);
        if (lane >= off) s += t;
    }
    if (lane < nb) blockoff[lane] = s - v;
}

__global__ __launch_bounds__(1024) void scanC(int* __restrict__ rowptr,
                                              const int* __restrict__ blockoff, int n) {
    int idx = blockIdx.x * 1024 + threadIdx.x;
    if (idx == 0) rowptr[0] = 0;
    if (idx < n) rowptr[idx + 1] += blockoff[blockIdx.x];
}

__global__ void scatter_edges(const int* __restrict__ row, const int* __restrict__ col,
                              const int* __restrict__ rowptr, int* __restrict__ cur,
                              int* __restrict__ csr, int e) {
    int i = blockIdx.x * blockDim.x + threadIdx.x;
    if (i < e) {
        int r = row[i];
        int p = atomicAdd(&cur[r], 1);
        csr[rowptr[r] + p] = col[i];
    }
}

// ---------------- weight conversion / transposition to f16 ----------------
// conv_w [L*K][d][o] -> wt16 [L*K][o][d]
// fc0_w  [128][96]   -> fc0t [96][128]
// fc1_w  [96][40]    -> fc1t [48][96] (zero-padded o>=40)

#define CONV_TOT (L_LAYERS * K_EXP * H * H)   // 294912
#define FC0_TOT  (DIN * H)                    // 12288
#define FC1_TOT  (48 * H)                     // 4608

__global__ void convert_all(const float* __restrict__ conv_w,
                            const float* __restrict__ fc0_w,
                            const float* __restrict__ fc1_w,
                            f16* __restrict__ wt16, f16* __restrict__ fc0t,
                            f16* __restrict__ fc1t) {
    int i = blockIdx.x * blockDim.x + threadIdx.x;
    if (i < CONV_TOT) {
        int o = i % H;
        int t = i / H;
        int d = t % H;
        int lk = t / H;
        wt16[(size_t)lk * H * H + o * H + d] = (f16)conv_w[i];
    } else if (i < CONV_TOT + FC0_TOT) {
        int j = i - CONV_TOT;      // j = d*96+o
        int o = j % H, d = j / H;
        fc0t[o * DIN + d] = (f16)fc0_w[j];
    } else if (i < CONV_TOT + FC0_TOT + FC1_TOT) {
        int j = i - CONV_TOT - FC0_TOT;  // target index [o][d]
        int o = j / H, d = j % H;
        fc1t[j] = (o < C_OUT) ? (f16)fc1_w[d * C_OUT + o] : (f16)0.f;
    }
}

// ---------------- SpMM: hi16[r] = sum over edges (r,c) of h16[c] ----------------
// 16 lanes per row, each lane owns dwords (f16x2) li, li+16, li+32 of the 48-dword row.

__global__ __launch_bounds__(256) void spmm_kernel(const unsigned int* __restrict__ h16d,
                                                   const int* __restrict__ rowptr,
                                                   const int* __restrict__ csr,
                                                   unsigned int* __restrict__ hi16d, int n) {
    int r  = blockIdx.x * 16 + (threadIdx.x >> 4);
    int li = threadIdx.x & 15;
    if (r >= n) return;
    int start = rowptr[r], end = rowptr[r + 1];
    float a0 = 0.f, a1 = 0.f, a2 = 0.f, a3 = 0.f, a4 = 0.f, a5 = 0.f;
    for (int j0 = start; j0 < end; j0 += 16) {
        int m = end - j0; if (m > 16) m = 16;
        int c = 0;
        if (li < m) c = csr[j0 + li];
        for (int t = 0; t < m; t++) {
            int cc = __shfl(c, t, 16);
            const unsigned int* hp = h16d + (size_t)cc * 48;
            unsigned int u0 = hp[li], u1 = hp[li + 16], u2 = hp[li + 32];
            f16x2 v0 = __builtin_bit_cast(f16x2, u0);
            f16x2 v1 = __builtin_bit_cast(f16x2, u1);
            f16x2 v2 = __builtin_bit_cast(f16x2, u2);
            a0 += (float)v0.x; a1 += (float)v0.y;
            a2 += (float)v1.x; a3 += (float)v1.y;
            a4 += (float)v2.x; a5 += (float)v2.y;
        }
    }
    unsigned int* op = hi16d + (size_t)r * 48;
    f16x2 o0 = {(f16)a0, (f16)a1};
    f16x2 o1 = {(f16)a2, (f16)a3};
    f16x2 o2 = {(f16)a4, (f16)a5};
    op[li]      = __builtin_bit_cast(unsigned int, o0);
    op[li + 16] = __builtin_bit_cast(unsigned int, o1);
    op[li + 32] = __builtin_bit_cast(unsigned int, o2);
}

// ---------------- ctx + softmax: thread per node, fp16 h, ctx_w in LDS ----------------

__global__ __launch_bounds__(256) void ctx_softmax(const f16* __restrict__ h16,
                                                   const float* __restrict__ cw,
                                                   const float* __restrict__ cb,
                                                   float* __restrict__ z, int n) {
    __shared__ float ws[H * K_EXP];   // 3 KB
    __shared__ float bs[K_EXP];
    int tid = threadIdx.x;
    for (int t = tid; t < H * K_EXP; t += 256) ws[t] = cw[t];
    if (tid < K_EXP) bs[tid] = cb[tid];
    __syncthreads();
    int node = blockIdx.x * 256 + tid;
    if (node >= n) return;
    float acc[K_EXP];
    #pragma unroll
    for (int k = 0; k < K_EXP; k++) acc[k] = bs[k];
    const f16* hr = h16 + (size_t)node * H;
    #pragma unroll 3
    for (int c8 = 0; c8 < 12; c8++) {
        f16x8 v = *(const f16x8*)(hr + c8 * 8);
        #pragma unroll
        for (int j = 0; j < 8; j++) {
            float hv = (float)v[j];
            int d = c8 * 8 + j;
            #pragma unroll
            for (int k = 0; k < K_EXP; k++) acc[k] += hv * ws[d * K_EXP + k];
        }
    }
    float mx = acc[0];
    #pragma unroll
    for (int k = 1; k < K_EXP; k++) mx = fmaxf(mx, acc[k]);
    float s = 0.f;
    #pragma unroll
    for (int k = 0; k < K_EXP; k++) { acc[k] = __expf(acc[k] - mx); s += acc[k]; }
    float inv = 1.f / s;
    f32x4 z0 = {acc[0] * inv, acc[1] * inv, acc[2] * inv, acc[3] * inv};
    f32x4 z1 = {acc[4] * inv, acc[5] * inv, acc[6] * inv, acc[7] * inv};
    *(f32x4*)(z + (size_t)node * K_EXP)     = z0;
    *(f32x4*)(z + (size_t)node * K_EXP + 4) = z1;
}

// ---------------- fc0 via fp16 MFMA: h = relu(x @ W + b) ----------------
// 64 rows x 96 cols per block, 4 waves; K=128 (4 k-steps of 32).

#define FPAD 136   // 128 + 8

__global__ __launch_bounds__(256) void fc0_kernel(const float* __restrict__ x,
                                                  const f16* __restrict__ fc0t,  // [96][128]
                                                  const float* __restrict__ b,
                                                  float* __restrict__ h,
                                                  f16* __restrict__ h16, int n) {
    __shared__ f16 As[64 * FPAD];
    __shared__ f16 Ws[96 * FPAD];
    int tid = threadIdx.x;
    int l = tid & 63, w = tid >> 6;
    int quad = l >> 4, lc = l & 15;
    int row0 = blockIdx.x * 64;

    // stage A: 64 x 128 fp32 -> f16 (float4 chunks)
    for (int t = tid; t < 2048; t += 256) {
        int m = t >> 5, c4 = (t & 31) * 4;
        int gr = row0 + m;
        float4 v = {0.f, 0.f, 0.f, 0.f};
        if (gr < n) v = *(const float4*)(x + (size_t)gr * DIN + c4);
        f16x4 h4 = {(f16)v.x, (f16)v.y, (f16)v.z, (f16)v.w};
        *(f16x4*)&As[m * FPAD + c4] = h4;
    }
    // stage W: 96 x 128 f16
    for (int t = tid; t < 1536; t += 256) {
        int o = t >> 4, c8 = (t & 15) * 8;
        *(f16x8*)&Ws[o * FPAD + c8] = *(const f16x8*)(fc0t + o * DIN + c8);
    }
    __syncthreads();

    f16x8 afr[4];
    #pragma unroll
    for (int ks = 0; ks < 4; ks++)
        afr[ks] = *(const f16x8*)&As[(16 * w + lc) * FPAD + ks * 32 + quad * 8];

    f32x4 acc[6] = {};
    #pragma unroll
    for (int ct = 0; ct < 6; ct++) {
        #pragma unroll
        for (int ks = 0; ks < 4; ks++) {
            f16x8 bfr = *(const f16x8*)&Ws[(ct * 16 + lc) * FPAD + ks * 32 + quad * 8];
            acc[ct] = __builtin_amdgcn_mfma_f32_16x16x32_f16(afr[ks], bfr, acc[ct], 0, 0, 0);
        }
    }

    int m0 = 16 * w + quad * 4;
    #pragma unroll
    for (int r = 0; r < 4; r++) {
        int gr = row0 + m0 + r;
        if (gr < n) {
            #pragma unroll
            for (int ct = 0; ct < 6; ct++) {
                int o = ct * 16 + lc;
                float v = fmaxf(acc[ct][r] + b[o], 0.f);
                h[(size_t)gr * H + o] = v;
                h16[(size_t)gr * H + o] = (f16)v;
            }
        }
    }
}

// ---------------- expert GEMM via fp16 MFMA ----------------

#define APAD 104   // 96 + 8

__global__ __launch_bounds__(256) void expert_gemm(const f16* __restrict__ hi16,
                                                   const float* __restrict__ hin,
                                                   const f16* __restrict__ wt,     // [K][o][d]
                                                   const float* __restrict__ z,
                                                   float* __restrict__ hout,
                                                   f16* __restrict__ hout16, int n) {
    __shared__ f16 As[64 * APAD];
    __shared__ f16 Ws[96 * APAD];
    __shared__ float Zs[64 * 8];

    int tid = threadIdx.x;
    int l = tid & 63, w = tid >> 6;
    int quad = l >> 4, lc = l & 15;
    int row0 = blockIdx.x * 64;

    for (int t = tid; t < 768; t += 256) {
        int m = t / 12, c8 = (t % 12) * 8;
        int gr = row0 + m;
        f16x8 v = {};
        if (gr < n) v = *(const f16x8*)(hi16 + (size_t)gr * H + c8);
        *(f16x8*)&As[m * APAD + c8] = v;
    }
    for (int t = tid; t < 512; t += 256) {
        int m = t >> 3, k = t & 7;
        int gr = row0 + m;
        Zs[m * 8 + k] = (gr < n) ? z[(size_t)gr * K_EXP + k] : 0.f;
    }
    __syncthreads();

    f16x8 afr[3];
    #pragma unroll
    for (int ks = 0; ks < 3; ks++)
        afr[ks] = *(const f16x8*)&As[(16 * w + lc) * APAD + ks * 32 + quad * 8];

    f32x4 acc[6] = {};

    for (int k = 0; k < K_EXP; k++) {
        __syncthreads();
        const f16* wk = wt + (size_t)k * H * H;
        for (int t = tid; t < 1152; t += 256) {
            int o = t / 12, c8 = (t % 12) * 8;
            *(f16x8*)&Ws[o * APAD + c8] = *(const f16x8*)(wk + o * H + c8);
        }
        __syncthreads();

        float z0 = Zs[(16 * w + quad * 4 + 0) * 8 + k];
        float z1 = Zs[(16 * w + quad * 4 + 1) * 8 + k];
        float z2 = Zs[(16 * w + quad * 4 + 2) * 8 + k];
        float z3 = Zs[(16 * w + quad * 4 + 3) * 8 + k];

        #pragma unroll
        for (int ct = 0; ct < 6; ct++) {
            f32x4 tmp = {};
            #pragma unroll
            for (int ks = 0; ks < 3; ks++) {
                f16x8 bfr = *(const f16x8*)&Ws[(ct * 16 + lc) * APAD + ks * 32 + quad * 8];
                tmp = __builtin_amdgcn_mfma_f32_16x16x32_f16(afr[ks], bfr, tmp, 0, 0, 0);
            }
            acc[ct][0] += z0 * tmp[0];
            acc[ct][1] += z1 * tmp[1];
            acc[ct][2] += z2 * tmp[2];
            acc[ct][3] += z3 * tmp[3];
        }
    }

    int m0 = 16 * w + quad * 4;
    #pragma unroll
    for (int r = 0; r < 4; r++) {
        int gr = row0 + m0 + r;
        if (gr < n) {
            #pragma unroll
            for (int ct = 0; ct < 6; ct++) {
                int o = ct * 16 + lc;
                float v = fmaxf(acc[ct][r] + hin[(size_t)gr * H + o], 0.f);
                hout[(size_t)gr * H + o] = v;
                hout16[(size_t)gr * H + o] = (f16)v;
            }
        }
    }
}

// ---------------- fc1 via fp16 MFMA: out = h @ W + b ----------------
// 64 rows x 48 cols (40 valid), K=96.

__global__ __launch_bounds__(256) void fc1_kernel(const f16* __restrict__ h16,
                                                  const f16* __restrict__ fc1t,  // [48][96]
                                                  const float* __restrict__ b,
                                                  float* __restrict__ out, int n) {
    __shared__ f16 As[64 * APAD];
    __shared__ f16 Ws[48 * APAD];
    int tid = threadIdx.x;
    int l = tid & 63, w = tid >> 6;
    int quad = l >> 4, lc = l & 15;
    int row0 = blockIdx.x * 64;

    for (int t = tid; t < 768; t += 256) {
        int m = t / 12, c8 = (t % 12) * 8;
        int gr = row0 + m;
        f16x8 v = {};
        if (gr < n) v = *(const f16x8*)(h16 + (size_t)gr * H + c8);
        *(f16x8*)&As[m * APAD + c8] = v;
    }
    for (int t = tid; t < 576; t += 256) {
        int o = t / 12, c8 = (t % 12) * 8;
        *(f16x8*)&Ws[o * APAD + c8] = *(const f16x8*)(fc1t + o * H + c8);
    }
    __syncthreads();

    f16x8 afr[3];
    #pragma unroll
    for (int ks = 0; ks < 3; ks++)
        afr[ks] = *(const f16x8*)&As[(16 * w + lc) * APAD + ks * 32 + quad * 8];

    f32x4 acc[3] = {};
    #pragma unroll
    for (int ct = 0; ct < 3; ct++) {
        #pragma unroll
        for (int ks = 0; ks < 3; ks++) {
            f16x8 bfr = *(const f16x8*)&Ws[(ct * 16 + lc) * APAD + ks * 32 + quad * 8];
            acc[ct] = __builtin_amdgcn_mfma_f32_16x16x32_f16(afr[ks], bfr, acc[ct], 0, 0, 0);
        }
    }

    int m0 = 16 * w + quad * 4;
    #pragma unroll
    for (int r = 0; r < 4; r++) {
        int gr = row0 + m0 + r;
        if (gr < n) {
            #pragma unroll
            for (int ct = 0; ct < 3; ct++) {
                int o = ct * 16 + lc;
                if (o < C_OUT)
                    out[(size_t)gr * C_OUT + o] = acc[ct][r] + b[o];
            }
        }
    }
}

// ---------------- launch ----------------

extern "C" void kernel_launch(void* const* d_in, const int* in_sizes, int n_in,
                              void* d_out, int out_size, void* d_ws, size_t ws_size,
                              hipStream_t stream) {
    const float* x      = (const float*)d_in[0];
    const int*   ei     = (const int*)d_in[1];
    const float* fc0_w  = (const float*)d_in[2];
    const float* fc0_b  = (const float*)d_in[3];
    const float* fc1_w  = (const float*)d_in[4];
    const float* fc1_b  = (const float*)d_in[5];
    const float* ctx_w  = (const float*)d_in[6];
    const float* ctx_b  = (const float*)d_in[7];
    const float* conv_w = (const float*)d_in[8];
    float* out = (float*)d_out;

    const size_t NH = (size_t)N_NODES * H;

    float* h0   = (float*)d_ws;
    float* h1   = h0 + NH;
    float* zbuf = h1 + NH;
    f16*   h16  = (f16*)(zbuf + (size_t)N_NODES * K_EXP);
    f16*   hi16 = h16 + NH;
    f16*   wt16 = hi16 + NH;
    f16*   fc0t = wt16 + CONV_TOT;
    f16*   fc1t = fc0t + FC0_TOT;
    int* rowptr = (int*)(fc1t + FC1_TOT);
    int* deg    = rowptr + (N_NODES + 1);
    int* cur    = deg + N_NODES;
    int* csr    = cur + N_NODES;
    int* partial  = csr + N_EDGES;
    int* blockoff = partial + 64;

    const int* row = ei;
    const int* col = ei + N_EDGES;

    hipMemsetAsync(deg, 0, sizeof(int) * 2 * N_NODES, stream);

    count_deg<<<(N_EDGES + 255) / 256, 256, 0, stream>>>(row, deg, N_EDGES);
    int nsb = (N_NODES + 1023) / 1024;   // 49
    scanA<<<nsb, 1024, 0, stream>>>(deg, rowptr, partial, N_NODES);
    scanB<<<1, 64, 0, stream>>>(partial, blockoff, nsb);
    scanC<<<nsb, 1024, 0, stream>>>(rowptr, blockoff, N_NODES);
    scatter_edges<<<(N_EDGES + 255) / 256, 256, 0, stream>>>(row, col, rowptr, cur, csr, N_EDGES);

    int ctotal = CONV_TOT + FC0_TOT + FC1_TOT;
    convert_all<<<(ctotal + 255) / 256, 256, 0, stream>>>(conv_w, fc0_w, fc1_w, wt16, fc0t, fc1t);

    int gemm_grid = (N_NODES + 63) / 64;
    fc0_kernel<<<gemm_grid, 256, 0, stream>>>(x, fc0t, fc0_b, h0, h16, N_NODES);

    float* hcur = h0;
    float* hnext = h1;
    for (int i = 0; i < L_LAYERS; i++) {
        ctx_softmax<<<(N_NODES + 255) / 256, 256, 0, stream>>>(
            h16, ctx_w + (size_t)i * H * K_EXP, ctx_b + (size_t)i * K_EXP, zbuf, N_NODES);
        spmm_kernel<<<(N_NODES + 15) / 16, 256, 0, stream>>>(
            (const unsigned int*)h16, rowptr, csr, (unsigned int*)hi16, N_NODES);
        expert_gemm<<<gemm_grid, 256, 0, stream>>>(
            hi16, hcur, wt16 + (size_t)i * K_EXP * H * H, zbuf, hnext, h16, N_NODES);
        float* t = hcur; hcur = hnext; hnext = t;
    }
    fc1_kernel<<<gemm_grid, 256, 0, stream>>>(h16, fc1t, fc1_b, out, N_NODES);
}